// Round 1
// baseline (219.149 us; speedup 1.0000x reference)
//
#include <hip/hip_runtime.h>
#include <hip/hip_fp16.h>

// Trilinear 3D-LUT apply (33^3, 3ch) over (32,3,512,512) fp32 image.
// Strategy: expand LUT into a per-cell table (32^3 cells, 8 corners x 3ch as
// fp16, padded to 64B = one cache line per cell). Main kernel: 1 thread/pixel,
// 3x dwordx4 gather from the cell line + lerp. Output tuple = (lut, out).

constexpr int D = 33;
constexpr int LUT_C_STRIDE = D * D * D;        // 35937
constexpr int LUT_N = 3 * LUT_C_STRIDE;        // 107811
constexpr int HW = 512 * 512;                  // 262144
constexpr int NPIX = 32 * HW;                  // 8388608 pixels
constexpr int NCELL = 32 * 32 * 32;            // 32768
constexpr size_t TABLE_BYTES = (size_t)NCELL * 64;  // 2 MiB

__global__ __launch_bounds__(256)
void build_cells_kernel(const float* __restrict__ lut, __half* __restrict__ tbl) {
    int cell = blockIdx.x * 256 + threadIdx.x;
    if (cell >= NCELL) return;
    int x0 = cell & 31;
    int y0 = (cell >> 5) & 31;
    int z0 = cell >> 10;
    int base = z0 * (D * D) + y0 * D + x0;
    __half* dst = tbl + (size_t)cell * 32;  // 32 halves = 64B per cell
#pragma unroll
    for (int c = 0; c < 3; ++c) {
        const float* L = lut + c * LUT_C_STRIDE + base;
        dst[c * 8 + 0] = __float2half(L[0]);
        dst[c * 8 + 1] = __float2half(L[1]);
        dst[c * 8 + 2] = __float2half(L[D]);
        dst[c * 8 + 3] = __float2half(L[D + 1]);
        dst[c * 8 + 4] = __float2half(L[D * D]);
        dst[c * 8 + 5] = __float2half(L[D * D + 1]);
        dst[c * 8 + 6] = __float2half(L[D * D + D]);
        dst[c * 8 + 7] = __float2half(L[D * D + D + 1]);
    }
}

__device__ __forceinline__ float lerp3(const float* v, float wx, float wy, float wz) {
    float c00 = v[0] + wx * (v[1] - v[0]);
    float c01 = v[2] + wx * (v[3] - v[2]);
    float c10 = v[4] + wx * (v[5] - v[4]);
    float c11 = v[6] + wx * (v[7] - v[6]);
    float c0 = c00 + wy * (c01 - c00);
    float c1 = c10 + wy * (c11 - c10);
    return c0 + wz * (c1 - c0);
}

__global__ __launch_bounds__(256)
void trilerp_cells_kernel(const uint4* __restrict__ tbl,
                          const float* __restrict__ img,
                          float* __restrict__ out) {
    int p = blockIdx.x * 256 + threadIdx.x;
    if (p >= NPIX) return;
    int b = p >> 18;           // / HW
    int hw = p & (HW - 1);
    const float* ip = img + (size_t)b * (3 * HW) + hw;
    float r = ip[0];
    float g = ip[HW];
    float bl = ip[2 * HW];

    const float s = 32.0f;
    float x = fminf(fmaxf(r * s, 0.0f), s);
    float y = fminf(fmaxf(g * s, 0.0f), s);
    float z = fminf(fmaxf(bl * s, 0.0f), s);
    float xf = fminf(floorf(x), 31.0f);
    float yf = fminf(floorf(y), 31.0f);
    float zf = fminf(floorf(z), 31.0f);
    float wx = x - xf, wy = y - yf, wz = z - zf;
    int ix = (int)xf, iy = (int)yf, iz = (int)zf;
    int cell = (iz << 10) | (iy << 5) | ix;

    // 48B of one 64B-aligned line: 3x dwordx4
    const uint4* cp = tbl + (size_t)cell * 4;
    union {
        uint4 q[3];
        __half h[24];
    } u;
    u.q[0] = cp[0];
    u.q[1] = cp[1];
    u.q[2] = cp[2];

    float v[8];
    float res[3];
#pragma unroll
    for (int c = 0; c < 3; ++c) {
#pragma unroll
        for (int i = 0; i < 8; ++i) v[i] = __half2float(u.h[c * 8 + i]);
        res[c] = lerp3(v, wx, wy, wz);
    }

    float* op = out + (size_t)b * (3 * HW) + hw;
    op[0] = res[0];
    op[HW] = res[1];
    op[2 * HW] = res[2];
}

// Fallback: direct fp32 LUT reads (24 scalar gathers/pixel). Only used if
// ws_size is too small for the 2 MiB cell table.
__global__ __launch_bounds__(256)
void trilerp_direct_kernel(const float* __restrict__ lut,
                           const float* __restrict__ img,
                           float* __restrict__ out) {
    int p = blockIdx.x * 256 + threadIdx.x;
    if (p >= NPIX) return;
    int b = p >> 18;
    int hw = p & (HW - 1);
    const float* ip = img + (size_t)b * (3 * HW) + hw;
    float r = ip[0];
    float g = ip[HW];
    float bl = ip[2 * HW];

    const float s = 32.0f;
    float x = fminf(fmaxf(r * s, 0.0f), s);
    float y = fminf(fmaxf(g * s, 0.0f), s);
    float z = fminf(fmaxf(bl * s, 0.0f), s);
    float xf = fminf(floorf(x), 31.0f);
    float yf = fminf(floorf(y), 31.0f);
    float zf = fminf(floorf(z), 31.0f);
    float wx = x - xf, wy = y - yf, wz = z - zf;
    int ix = (int)xf, iy = (int)yf, iz = (int)zf;
    int base = iz * (D * D) + iy * D + ix;

    float* op = out + (size_t)b * (3 * HW) + hw;
#pragma unroll
    for (int c = 0; c < 3; ++c) {
        const float* L = lut + c * LUT_C_STRIDE + base;
        float v[8];
        v[0] = L[0];
        v[1] = L[1];
        v[2] = L[D];
        v[3] = L[D + 1];
        v[4] = L[D * D];
        v[5] = L[D * D + 1];
        v[6] = L[D * D + D];
        v[7] = L[D * D + D + 1];
        op[c * HW] = lerp3(v, wx, wy, wz);
    }
}

extern "C" void kernel_launch(void* const* d_in, const int* in_sizes, int n_in,
                              void* d_out, int out_size, void* d_ws, size_t ws_size,
                              hipStream_t stream) {
    const float* lut = (const float*)d_in[0];
    const float* img = (const float*)d_in[1];
    float* out = (float*)d_out;

    // Output 0: exact fp32 copy of the LUT.
    hipMemcpyAsync(d_out, d_in[0], (size_t)LUT_N * sizeof(float),
                   hipMemcpyDeviceToDevice, stream);

    float* out_img = out + LUT_N;

    if (ws_size >= TABLE_BYTES) {
        build_cells_kernel<<<(NCELL + 255) / 256, 256, 0, stream>>>(
            lut, (__half*)d_ws);
        trilerp_cells_kernel<<<(NPIX + 255) / 256, 256, 0, stream>>>(
            (const uint4*)d_ws, img, out_img);
    } else {
        trilerp_direct_kernel<<<(NPIX + 255) / 256, 256, 0, stream>>>(
            lut, img, out_img);
    }
}